// Round 5
// baseline (41.702 us; speedup 1.0000x reference)
//
#include <hip/hip_runtime.h>
#include <math.h>

#define NP   512
#define NT   1024
#define NS   25
#define NPS  (NP*NS)            // 12800
#define MASKN (NP*NT*NS)        // 13107200

// ws layout (in doubles):
//  dsA  [NPS][4]   @ 0        (ray d-vectors, AoS, pad to 4)
//  pd   [NP][4]    @ 51200    (points f64)
//  nx   [NT]       @ 53248
//  ny   [NT]       @ 54272
//  nz   [NT]       @ 55296
//  kk   [NT]       @ 56320
//  Wtab [NT][10]   @ 57344    (WG0..2, WB0..2, WA0..2, pad; sign-folded)
//  emptyMask u32[NP] at byte offset 67584*8
#define DSA_OFF  0
#define PD_OFF   51200
#define NX_OFF   53248
#define NY_OFF   54272
#define NZ_OFF   55296
#define KK_OFF   56320
#define W_OFF    57344
#define EMPTY_OFF ((size_t)67584 * 8)

#define NROWS 207   // W rows spanned by 5 lines: ceil(5*1024/25)+2

__device__ __forceinline__ double sgn(double x) {
    return (x > 0.0) ? 1.0 : ((x < 0.0) ? -1.0 : 0.0);
}

// Fused prep: blocks 0..49 rays, 50..53 triangle tables, 54 scatter+emptyMask.
__global__ void prep_all(const float* __restrict__ p,
                         const float* __restrict__ l,
                         const float* __restrict__ hemi,
                         const float* __restrict__ V,
                         const int* __restrict__ indices,
                         const int* __restrict__ pointindex,
                         const float* __restrict__ COL,
                         const float* __restrict__ OPA,
                         double* __restrict__ ws,
                         unsigned* __restrict__ emptyMask,
                         float* __restrict__ out) {
    const int b = blockIdx.x, t = threadIdx.x;
    if (b < 50) {
        int idx = b * 256 + t;                 // < 12800 exactly
        int pi = idx / NS, si = idx % NS;
        double px = p[pi*3+0], py = p[pi*3+1], pz = p[pi*3+2];
        double lx = l[0], ly = l[1], lz = l[2];
        double ux = lx - px, uy = ly - py, uz = lz - pz;
        double nrm = sqrt(ux*ux + uy*uy + uz*uz);
        ux /= nrm; uy /= nrm; uz /= nrm;
        double c = -uy;
        double wx = -uz, wz = ux;              // w = cross((0,-1,0), u_hat), wy=0
        double m01 = -wz, m10 = wz, m12 = -wx, m21 = wx;
        double q00 = m01*m10;
        double q02 = m01*m12;
        double q11 = m10*m01 + m12*m21;
        double q20 = m21*m10;
        double q22 = m21*m12;
        double ic = 1.0 + c;
        double r00 = 1.0 + q00/ic, r01 = m01,            r02 = q02/ic;
        double r10 = m10,          r11 = 1.0 + q11/ic,   r12 = m12;
        double r20 = q20/ic,       r21 = m21,            r22 = 1.0 + q22/ic;
        double hx = hemi[si*3+0], hy = hemi[si*3+1], hz = hemi[si*3+2];
        double lhx = r00*hx + r01*hy + r02*hz + lx;
        double lhy = r10*hx + r11*hy + r12*hz + ly;
        double lhz = r20*hx + r21*hy + r22*hz + lz;
        double* dsA = ws + DSA_OFF;
        dsA[idx*4+0] = lhx - px;
        dsA[idx*4+1] = lhy - py;
        dsA[idx*4+2] = lhz - pz;
        dsA[idx*4+3] = 0.0;
    } else if (b < 54) {
        int n = (b - 50) * 256 + t;            // < 1024 exactly
        const float* v = V + n*12;
        double a0=v[0], a1=v[1], a2=v[2];
        double b0=v[3], b1=v[4], b2=v[5];
        double c0=v[6], c1=v[7], c2=v[8];
        double v3x=v[9], v3y=v[10], v3z=v[11];
        double e1x=b0-a0, e1y=b1-a1, e1z=b2-a2;
        double e2x=c0-a0, e2y=c1-a1, e2z=c2-a2;
        double cx = e1y*e2z - e1z*e2y;
        double cy = e1z*e2x - e1x*e2z;
        double cz = e1x*e2y - e1y*e2x;
        double nn = sqrt(cx*cx + cy*cy + cz*cz);
        double nx = cx/nn, ny = cy/nn, nz = cz/nn;
        double kk = -(nx*v3x + ny*v3y + nz*v3z);
        double Bv = a0*b2 - a2*b0;
        double Dv = a0*b1 - a1*b0;
        double Ec = a0*c2 - a2*c0;
        double G2 = a1*c0 - a0*c1;
        double Fc = Bv*G2;
        double gd = Dv*(Ec*Dv + Fc);
        double gq = Dv*gd;
        double dq = Dv*c0;
        double aq = a0*gq;
        double WGr0 = a1*Bv - a2*Dv, WGr1 = -(a0*Bv), WGr2 = a0*Dv;
        double dg = Dv*G2;
        double WBr0 = -(a1*gd) + dg*WGr0;
        double WBr1 =  a0*gd  + dg*WGr1;
        double WBr2 =            dg*WGr2;
        double dd = Dv*dq;
        double WAr0 = gq - b0*WBr0 - dd*WGr0;
        double WAr1 =    - b0*WBr1 - dd*WGr1;
        double WAr2 =    - b0*WBr2 - dd*WGr2;
        double sg = sgn(Dv*gd), sb = sgn(gq), sa = sgn(aq);
        ws[NX_OFF + n] = nx;
        ws[NY_OFF + n] = ny;
        ws[NZ_OFF + n] = nz;
        ws[KK_OFF + n] = kk;
        double* W = ws + W_OFF + n*10;
        W[0] = WGr0*sg; W[1] = WGr1*sg; W[2] = WGr2*sg;
        W[3] = WBr0*sb; W[4] = WBr1*sb; W[5] = WBr2*sb;
        W[6] = WAr0*sa; W[7] = WAr1*sa; W[8] = WAr2*sa;
        W[9] = 0.0;
    } else {
        emptyMask[t] = 0u;
        emptyMask[t + 256] = 0u;
        __syncthreads();
        for (int i = t; i < NP; i += 256) {
            int pidx = pointindex[i];
            int local = pidx & (NP - 1);
            int surf = indices[pidx*2 + 0];
            int mat  = indices[pidx*2 + 1];
            atomicOr(&emptyMask[local], 1u << surf);
            float* colOut = out + MASKN;
            float* opaOut = out + MASKN + 3*NP;
            float* refOut = out + MASKN + 4*NP;
            colOut[i*3+0] = COL[(surf*8+mat)*3+0];
            colOut[i*3+1] = COL[(surf*8+mat)*3+1];
            colOut[i*3+2] = COL[(surf*8+mat)*3+2];
            float o = OPA[surf*8+mat];
            opaOut[i] = fminf(fmaxf(o, 0.0f), 1.0f);
            refOut[i*3+0] = (float)((double)l[0] - (double)p[i*3+0]);
            refOut[i*3+1] = (float)((double)l[1] - (double)p[i*3+1]);
            refOut[i*3+2] = (float)((double)l[2] - (double)p[i*3+2]);
            double* pd = ws + PD_OFF;
            pd[i*4+0] = (double)p[i*3+0];
            pd[i*4+1] = (double)p[i*3+1];
            pd[i*4+2] = (double)p[i*3+2];
            pd[i*4+3] = 0.0;
        }
    }
}

// Block = 5 lines (q0..q0+4) of one point pp. Thread owns 4 n-positions
// across all 5 lines (20 elements). n-tables in registers (reused 5x),
// tt = o.n + kk line-independent (computed once), w row register-hoisted
// with predicated reload on nn increment.
template<bool HE>
__device__ __forceinline__ void lines_body(
        const double* __restrict__ ws, const double (*sW)[11],
        const double* sdx, const double* sdy, const double* sdz,
        const double (*sSv)[4],
        double ox, double oy, double oz,
        unsigned em, unsigned nn0, unsigned q0, unsigned pp, unsigned tid,
        float* __restrict__ out) {
    const unsigned n0 = tid * 4u;
    const double2 nxa = *(const double2*)(ws + NX_OFF + n0);
    const double2 nxb = *(const double2*)(ws + NX_OFF + n0 + 2);
    const double2 nya = *(const double2*)(ws + NY_OFF + n0);
    const double2 nyb = *(const double2*)(ws + NY_OFF + n0 + 2);
    const double2 nza = *(const double2*)(ws + NZ_OFF + n0);
    const double2 nzb = *(const double2*)(ws + NZ_OFF + n0 + 2);
    const double2 kka = *(const double2*)(ws + KK_OFF + n0);
    const double2 kkb = *(const double2*)(ws + KK_OFF + n0 + 2);

    double nxk[4], nyk[4], nzk[4], ttk[4];
    #pragma unroll
    for (int k = 0; k < 4; ++k) {
        const double nxv = (k < 2) ? (k ? nxa.y : nxa.x) : (k == 3 ? nxb.y : nxb.x);
        const double nyv = (k < 2) ? (k ? nya.y : nya.x) : (k == 3 ? nyb.y : nyb.x);
        const double nzv = (k < 2) ? (k ? nza.y : nza.x) : (k == 3 ? nzb.y : nzb.x);
        const double kkv = (k < 2) ? (k ? kka.y : kka.x) : (k == 3 ? kkb.y : kkb.x);
        nxk[k] = nxv; nyk[k] = nyv; nzk[k] = nzv;
        ttk[k] = fma(oz, nzv, fma(oy, nyv, fma(ox, nxv, kkv)));   // nt = -tt
    }

    #pragma unroll
    for (int L = 0; L < 5; ++L) {
        const double sx = sSv[L][0], sy = sSv[L][1], sz = sSv[L][2];
        unsigned rem = ((q0 + (unsigned)L) << 10) + n0;
        unsigned nn = rem / 25u;
        unsigned ss = rem - nn * 25u;
        const double* wr = sW[nn - nn0];
        double w0 = wr[0], w1 = wr[1], w2 = wr[2];
        double w3 = wr[3], w4 = wr[4], w5 = wr[5];
        double w6 = wr[6], w7 = wr[7], w8 = wr[8];

        float res[4];
        #pragma unroll
        for (int k = 0; k < 4; ++k) {
            const double tt = ttk[k];
            const double vd = fma(sz, nzk[k], fma(sy, nyk[k], sx * nxk[k]));
            const double e1 = fma(1e-4, vd, -tt);   // t > -1e-4
            const double e2 = vd + tt;              // t < 1

            const double dxv = sdx[ss], dyv = sdy[ss], dzv = sdz[ss];
            const double R0 = fma(-tt, dxv, vd * ox);   // = vd * r0
            const double R1 = fma(-tt, dyv, vd * oy);
            const double R2 = fma(-tt, dzv, vd * oz);

            const double dG = fma(R2, w2, fma(R1, w1, R0 * w0));
            const double dB = fma(R2, w5, fma(R1, w4, R0 * w3));
            const double dA = fma(R2, w8, fma(R1, w7, R0 * w6));

            const int hv = __double2hiint(vd);
            int m = (__double2hiint(e1) ^ hv) | (__double2hiint(e2) ^ hv)
                  | (__double2hiint(dG) ^ hv) | (__double2hiint(dB) ^ hv)
                  | (__double2hiint(dA) ^ hv);
            bool ok = (m >= 0);
            if (HE) ok = ok && !((nn < 8u) && ((em >> nn) & 1u));
            res[k] = ok ? 1.0f : 0.0f;

            if (k < 3) {
                if (++ss == 25u) {
                    ss = 0u; ++nn;
                    const double* wn = sW[nn - nn0];
                    w0 = wn[0]; w1 = wn[1]; w2 = wn[2];
                    w3 = wn[3]; w4 = wn[4]; w5 = wn[5];
                    w6 = wn[6]; w7 = wn[7]; w8 = wn[8];
                }
            }
        }
        *(float4*)(out + (((pp*25u + q0 + (unsigned)L) << 10) + n0)) =
            make_float4(res[0], res[1], res[2], res[3]);
    }
}

__global__ __launch_bounds__(256) void diffuse_main(
        const double* __restrict__ ws,
        const unsigned* __restrict__ emptyMask,
        float* __restrict__ out) {
    __shared__ double sW[NROWS][11];       // stride 11: conflict-free row window
    __shared__ double sdx[25], sdy[25], sdz[25];
    __shared__ double sSv[5][4];

    const unsigned pp = blockIdx.x / 5u;   // grid = 2560
    const unsigned g  = blockIdx.x - pp * 5u;
    const unsigned q0 = g * 5u;
    const unsigned nn0 = (q0 << 10) / 25u;
    const unsigned tid = threadIdx.x;

    const double* Wg = ws + W_OFF;
    for (unsigned i = tid; i < NROWS*5u; i += 256u) {
        unsigned row = i / 5u, col = i - row * 5u;
        unsigned gn = nn0 + row; if (gn > 1023u) gn = 1023u;
        const double2 v = *(const double2*)(Wg + gn*10u + col*2u);
        sW[row][col*2u]   = v.x;
        sW[row][col*2u+1] = v.y;
    }
    if (tid < 25u) {
        const double* dr = ws + DSA_OFF + (pp*25u + tid)*4u;
        sdx[tid] = dr[0]; sdy[tid] = dr[1]; sdz[tid] = dr[2];
    } else if (tid >= 32u && tid < 52u) {
        unsigned j = tid - 32u, L = j >> 2, c = j & 3u;
        sSv[L][c] = ws[DSA_OFF + (pp*25u + q0 + L)*4u + c];
    }
    const double ox = ws[PD_OFF + pp*4u + 0];
    const double oy = ws[PD_OFF + pp*4u + 1];
    const double oz = ws[PD_OFF + pp*4u + 2];
    const unsigned em = emptyMask[pp];
    __syncthreads();

    if (g == 0u)
        lines_body<true >(ws, sW, sdx, sdy, sdz, sSv, ox, oy, oz,
                          em, nn0, q0, pp, tid, out);
    else
        lines_body<false>(ws, sW, sdx, sdy, sdz, sSv, ox, oy, oz,
                          em, nn0, q0, pp, tid, out);
}

extern "C" void kernel_launch(void* const* d_in, const int* in_sizes, int n_in,
                              void* d_out, int out_size, void* d_ws, size_t ws_size,
                              hipStream_t stream) {
    const float* V         = (const float*)d_in[0];
    const int*   indices   = (const int*)  d_in[1];
    const int*   pointindex= (const int*)  d_in[2];
    const float* COL       = (const float*)d_in[3];
    const float* OPA       = (const float*)d_in[4];
    const float* p         = (const float*)d_in[5];
    const float* l         = (const float*)d_in[6];
    // d_in[7] = normals (unused), d_in[8] = it (unused)
    const float* hemi      = (const float*)d_in[9];

    float* out = (float*)d_out;
    double* ws = (double*)d_ws;
    unsigned* emptyMask = (unsigned*)((char*)d_ws + EMPTY_OFF);

    prep_all<<<55, 256, 0, stream>>>(p, l, hemi, V, indices, pointindex,
                                     COL, OPA, ws, emptyMask, out);
    diffuse_main<<<NP*5, 256, 0, stream>>>(ws, emptyMask, out);
}

// Round 6
// 40.163 us; speedup vs baseline: 1.0383x; 1.0383x over previous
//
#include <hip/hip_runtime.h>
#include <math.h>

#define NP   512
#define NT   1024
#define NS   25
#define NPS  (NP*NS)            // 12800
#define MASKN (NP*NT*NS)        // 13107200

// ws layout (in doubles):
//  dsA  [NPS][4]   @ 0        (ray d-vectors, AoS, pad to 4)
//  pd   [NP][4]    @ 51200    (points f64)
//  nx   [NT]       @ 53248
//  ny   [NT]       @ 54272
//  nz   [NT]       @ 55296
//  kk   [NT]       @ 56320
//  Wtab [NT][10]   @ 57344    (WG0..2, WB0..2, WA0..2, pad; sign-folded)
//  emptyMask u32[NP] at byte offset 67584*8
#define DSA_OFF  0
#define PD_OFF   51200
#define NX_OFF   53248
#define NY_OFF   54272
#define NZ_OFF   55296
#define KK_OFF   56320
#define W_OFF    57344
#define EMPTY_OFF ((size_t)67584 * 8)

__device__ __forceinline__ double sgn(double x) {
    return (x > 0.0) ? 1.0 : ((x < 0.0) ? -1.0 : 0.0);
}

// Fused prep: blocks 0..49 rays, 50..53 triangle tables, 54 scatter+emptyMask.
__global__ void prep_all(const float* __restrict__ p,
                         const float* __restrict__ l,
                         const float* __restrict__ hemi,
                         const float* __restrict__ V,
                         const int* __restrict__ indices,
                         const int* __restrict__ pointindex,
                         const float* __restrict__ COL,
                         const float* __restrict__ OPA,
                         double* __restrict__ ws,
                         unsigned* __restrict__ emptyMask,
                         float* __restrict__ out) {
    const int b = blockIdx.x, t = threadIdx.x;
    if (b < 50) {
        int idx = b * 256 + t;                 // < 12800 exactly
        int pi = idx / NS, si = idx % NS;
        double px = p[pi*3+0], py = p[pi*3+1], pz = p[pi*3+2];
        double lx = l[0], ly = l[1], lz = l[2];
        double ux = lx - px, uy = ly - py, uz = lz - pz;
        double nrm = sqrt(ux*ux + uy*uy + uz*uz);
        ux /= nrm; uy /= nrm; uz /= nrm;
        double c = -uy;
        double wx = -uz, wz = ux;              // w = cross((0,-1,0), u_hat), wy=0
        double m01 = -wz, m10 = wz, m12 = -wx, m21 = wx;
        double q00 = m01*m10;
        double q02 = m01*m12;
        double q11 = m10*m01 + m12*m21;
        double q20 = m21*m10;
        double q22 = m21*m12;
        double ic = 1.0 + c;
        double r00 = 1.0 + q00/ic, r01 = m01,            r02 = q02/ic;
        double r10 = m10,          r11 = 1.0 + q11/ic,   r12 = m12;
        double r20 = q20/ic,       r21 = m21,            r22 = 1.0 + q22/ic;
        double hx = hemi[si*3+0], hy = hemi[si*3+1], hz = hemi[si*3+2];
        double lhx = r00*hx + r01*hy + r02*hz + lx;
        double lhy = r10*hx + r11*hy + r12*hz + ly;
        double lhz = r20*hx + r21*hy + r22*hz + lz;
        double* dsA = ws + DSA_OFF;
        dsA[idx*4+0] = lhx - px;
        dsA[idx*4+1] = lhy - py;
        dsA[idx*4+2] = lhz - pz;
        dsA[idx*4+3] = 0.0;
    } else if (b < 54) {
        int n = (b - 50) * 256 + t;            // < 1024 exactly
        const float* v = V + n*12;
        double a0=v[0], a1=v[1], a2=v[2];
        double b0=v[3], b1=v[4], b2=v[5];
        double c0=v[6], c1=v[7], c2=v[8];
        double v3x=v[9], v3y=v[10], v3z=v[11];
        double e1x=b0-a0, e1y=b1-a1, e1z=b2-a2;
        double e2x=c0-a0, e2y=c1-a1, e2z=c2-a2;
        double cx = e1y*e2z - e1z*e2y;
        double cy = e1z*e2x - e1x*e2z;
        double cz = e1x*e2y - e1y*e2x;
        double nn = sqrt(cx*cx + cy*cy + cz*cz);
        double nx = cx/nn, ny = cy/nn, nz = cz/nn;
        double kk = -(nx*v3x + ny*v3y + nz*v3z);
        double Bv = a0*b2 - a2*b0;
        double Dv = a0*b1 - a1*b0;
        double Ec = a0*c2 - a2*c0;
        double G2 = a1*c0 - a0*c1;
        double Fc = Bv*G2;
        double gd = Dv*(Ec*Dv + Fc);
        double gq = Dv*gd;
        double dq = Dv*c0;
        double aq = a0*gq;
        double WGr0 = a1*Bv - a2*Dv, WGr1 = -(a0*Bv), WGr2 = a0*Dv;
        double dg = Dv*G2;
        double WBr0 = -(a1*gd) + dg*WGr0;
        double WBr1 =  a0*gd  + dg*WGr1;
        double WBr2 =            dg*WGr2;
        double dd = Dv*dq;
        double WAr0 = gq - b0*WBr0 - dd*WGr0;
        double WAr1 =    - b0*WBr1 - dd*WGr1;
        double WAr2 =    - b0*WBr2 - dd*WGr2;
        double sg = sgn(Dv*gd), sb = sgn(gq), sa = sgn(aq);
        ws[NX_OFF + n] = nx;
        ws[NY_OFF + n] = ny;
        ws[NZ_OFF + n] = nz;
        ws[KK_OFF + n] = kk;
        double* W = ws + W_OFF + n*10;
        W[0] = WGr0*sg; W[1] = WGr1*sg; W[2] = WGr2*sg;
        W[3] = WBr0*sb; W[4] = WBr1*sb; W[5] = WBr2*sb;
        W[6] = WAr0*sa; W[7] = WAr1*sa; W[8] = WAr2*sa;
        W[9] = 0.0;
    } else {
        emptyMask[t] = 0u;
        emptyMask[t + 256] = 0u;
        __syncthreads();
        for (int i = t; i < NP; i += 256) {
            int pidx = pointindex[i];
            int local = pidx & (NP - 1);
            int surf = indices[pidx*2 + 0];
            int mat  = indices[pidx*2 + 1];
            atomicOr(&emptyMask[local], 1u << surf);
            float* colOut = out + MASKN;
            float* opaOut = out + MASKN + 3*NP;
            float* refOut = out + MASKN + 4*NP;
            colOut[i*3+0] = COL[(surf*8+mat)*3+0];
            colOut[i*3+1] = COL[(surf*8+mat)*3+1];
            colOut[i*3+2] = COL[(surf*8+mat)*3+2];
            float o = OPA[surf*8+mat];
            opaOut[i] = fminf(fmaxf(o, 0.0f), 1.0f);
            refOut[i*3+0] = (float)((double)l[0] - (double)p[i*3+0]);
            refOut[i*3+1] = (float)((double)l[1] - (double)p[i*3+1]);
            refOut[i*3+2] = (float)((double)l[2] - (double)p[i*3+2]);
            double* pd = ws + PD_OFF;
            pd[i*4+0] = (double)p[i*3+0];
            pd[i*4+1] = (double)p[i*3+1];
            pd[i*4+2] = (double)p[i*3+2];
            pd[i*4+3] = 0.0;
        }
    }
}

// Round 6: de-stall version of the round-4 structure.
//  - n-table loads + broadcast scalars issued BEFORE LDS staging + barrier
//    (global latency hides under staging).
//  - Branchless inner loop: no divergent w-reload; per-element direct
//    indexed LDS reads; ss/nn wrap via select.
//  - __launch_bounds__(256,4) pins >=4 waves/SIMD (VGPR <= 128).
template<bool HE>
__device__ __forceinline__ void line_body(
        const double (*sW)[11],
        const double* sdx, const double* sdy, const double* sdz,
        double sx, double sy, double sz, double ox, double oy, double oz,
        const double2& nxa, const double2& nxb, const double2& nya, const double2& nyb,
        const double2& nza, const double2& nzb, const double2& kka, const double2& kkb,
        unsigned em, unsigned nn0, unsigned q, unsigned ps, unsigned tid,
        float* __restrict__ out) {
    const unsigned n0 = tid * 4u;
    const unsigned rem0 = (q << 10) + n0;
    unsigned nnk = rem0 / 25u;              // one divide per thread
    unsigned ssk = rem0 - nnk * 25u;

    float res[4];
    #pragma unroll
    for (int k = 0; k < 4; ++k) {
        const double nxv = (k < 2) ? (k ? nxa.y : nxa.x) : (k == 3 ? nxb.y : nxb.x);
        const double nyv = (k < 2) ? (k ? nya.y : nya.x) : (k == 3 ? nyb.y : nyb.x);
        const double nzv = (k < 2) ? (k ? nza.y : nza.x) : (k == 3 ? nzb.y : nzb.x);
        const double kkv = (k < 2) ? (k ? kka.y : kka.x) : (k == 3 ? kkb.y : kkb.x);

        const double vd = fma(sz, nzv, fma(sy, nyv, sx * nxv));
        const double tt = fma(oz, nzv, fma(oy, nyv, fma(ox, nxv, kkv))); // nt=-tt
        const double e1 = fma(1e-4, vd, -tt);   // t > -1e-4
        const double e2 = vd + tt;              // t < 1

        const double dxv = sdx[ssk], dyv = sdy[ssk], dzv = sdz[ssk];
        const double R0 = fma(-tt, dxv, vd * ox);   // = vd * r0
        const double R1 = fma(-tt, dyv, vd * oy);
        const double R2 = fma(-tt, dzv, vd * oz);

        const double* w = sW[nnk - nn0];
        const double dG = fma(R2, w[2], fma(R1, w[1], R0 * w[0]));
        const double dB = fma(R2, w[5], fma(R1, w[4], R0 * w[3]));
        const double dA = fma(R2, w[8], fma(R1, w[7], R0 * w[6]));

        // sign(x*vd) > 0 for all five <=> hi-bit of OR of sign xors is clear
        const int hv = __double2hiint(vd);
        int m = (__double2hiint(e1) ^ hv) | (__double2hiint(e2) ^ hv)
              | (__double2hiint(dG) ^ hv) | (__double2hiint(dB) ^ hv)
              | (__double2hiint(dA) ^ hv);
        bool ok = (m >= 0);
        if (HE) ok = ok && !((nnk < 8u) && ((em >> nnk) & 1u));
        res[k] = ok ? 1.0f : 0.0f;

        // branchless wrap (ssb <= 24, so at most one wrap across k=0..3)
        ssk += 1u;
        const bool wrap = (ssk == 25u);
        nnk += wrap ? 1u : 0u;
        ssk  = wrap ? 0u : ssk;
    }
    *(float4*)(out + ps*1024u + n0) = make_float4(res[0], res[1], res[2], res[3]);
}

__global__ __launch_bounds__(256, 4) void diffuse_main(
        const double* __restrict__ ws,
        const unsigned* __restrict__ emptyMask,
        float* __restrict__ out) {
    __shared__ double sW[42][11];          // stride 11: 22-bank step, no row alias
    __shared__ double sdx[25], sdy[25], sdz[25];

    const unsigned ps = blockIdx.x;
    const unsigned pp = ps / 25u;
    const unsigned q  = ps - pp * 25u;
    const unsigned nn0 = (q << 10) / 25u;
    const unsigned tid = threadIdx.x;

    // ---- prefetch: per-thread n-table loads issued FIRST (latency hides
    //      under staging + barrier) ----
    const unsigned n0 = tid * 4u;
    const double2 nxa = *(const double2*)(ws + NX_OFF + n0);
    const double2 nxb = *(const double2*)(ws + NX_OFF + n0 + 2);
    const double2 nya = *(const double2*)(ws + NY_OFF + n0);
    const double2 nyb = *(const double2*)(ws + NY_OFF + n0 + 2);
    const double2 nza = *(const double2*)(ws + NZ_OFF + n0);
    const double2 nzb = *(const double2*)(ws + NZ_OFF + n0 + 2);
    const double2 kka = *(const double2*)(ws + KK_OFF + n0);
    const double2 kkb = *(const double2*)(ws + KK_OFF + n0 + 2);
    // broadcast scalars (independent of LDS)
    const double sx = ws[DSA_OFF + ps*4u + 0];
    const double sy = ws[DSA_OFF + ps*4u + 1];
    const double sz = ws[DSA_OFF + ps*4u + 2];
    const double ox = ws[PD_OFF + pp*4u + 0];
    const double oy = ws[PD_OFF + pp*4u + 1];
    const double oz = ws[PD_OFF + pp*4u + 2];
    const unsigned em = (q == 0u) ? emptyMask[pp] : 0u;

    // ---- stage W-slice + ray d-vectors into LDS ----
    const double* Wg = ws + W_OFF;
    if (tid < 210u) {
        unsigned row = tid / 5u, col = tid - row * 5u;
        unsigned gn = nn0 + row; if (gn > 1023u) gn = 1023u;
        const double2 v = *(const double2*)(Wg + gn*10u + col*2u);
        sW[row][col*2u]   = v.x;
        sW[row][col*2u+1] = v.y;
    }
    if (tid < 25u) {
        const double* dr = ws + DSA_OFF + (pp*25u + tid)*4u;
        sdx[tid] = dr[0]; sdy[tid] = dr[1]; sdz[tid] = dr[2];
    }
    __syncthreads();

    if (q == 0u)
        line_body<true >(sW, sdx, sdy, sdz, sx, sy, sz, ox, oy, oz,
                         nxa, nxb, nya, nyb, nza, nzb, kka, kkb,
                         em, nn0, q, ps, tid, out);
    else
        line_body<false>(sW, sdx, sdy, sdz, sx, sy, sz, ox, oy, oz,
                         nxa, nxb, nya, nyb, nza, nzb, kka, kkb,
                         em, nn0, q, ps, tid, out);
}

extern "C" void kernel_launch(void* const* d_in, const int* in_sizes, int n_in,
                              void* d_out, int out_size, void* d_ws, size_t ws_size,
                              hipStream_t stream) {
    const float* V         = (const float*)d_in[0];
    const int*   indices   = (const int*)  d_in[1];
    const int*   pointindex= (const int*)  d_in[2];
    const float* COL       = (const float*)d_in[3];
    const float* OPA       = (const float*)d_in[4];
    const float* p         = (const float*)d_in[5];
    const float* l         = (const float*)d_in[6];
    // d_in[7] = normals (unused), d_in[8] = it (unused)
    const float* hemi      = (const float*)d_in[9];

    float* out = (float*)d_out;
    double* ws = (double*)d_ws;
    unsigned* emptyMask = (unsigned*)((char*)d_ws + EMPTY_OFF);

    prep_all<<<55, 256, 0, stream>>>(p, l, hemi, V, indices, pointindex,
                                     COL, OPA, ws, emptyMask, out);
    diffuse_main<<<NPS, 256, 0, stream>>>(ws, emptyMask, out);
}

// Round 7
// 33.642 us; speedup vs baseline: 1.2396x; 1.1938x over previous
//
#include <hip/hip_runtime.h>
#include <math.h>

#define NP   512
#define NT   1024
#define NS   25
#define NPS  (NP*NS)            // 12800
#define MASKN (NP*NT*NS)        // 13107200

// ---- f64 region (double offsets) ----
#define DSA_OFF  0              // dsA [NPS][4]
#define PD_OFF   51200          // pd  [NP][4]
#define NX_OFF   53248
#define NY_OFF   54272
#define NZ_OFF   55296
#define KK_OFF   56320
#define W_OFF    57344          // W64 [NT][10] sign-folded
#define EMPTY_OFF ((size_t)67584 * 8)      // u32[512]
// ---- f32 shadow region (float offsets from F32 base) ----
#define F32_BYTE_OFF (EMPTY_OFF + 2048)
#define FD_OFF   0              // d32  [NPS][4]
#define FPD_OFF  51200          // pd32 [NP][4]
#define FNX_OFF  53248
#define FNY_OFF  54272
#define FNZ_OFF  55296
#define FKK_OFF  56320
#define FW_OFF   57344          // W32 [NT][12], rows prescaled to sum|w|=1

#define CEPS 7.6293945e-06f     // 64 * 2^-23

__device__ __forceinline__ double sgn(double x) {
    return (x > 0.0) ? 1.0 : ((x < 0.0) ? -1.0 : 0.0);
}

// Fused prep: blocks 0..49 rays, 50..53 triangle tables, 54 scatter+emptyMask.
__global__ void prep_all(const float* __restrict__ p,
                         const float* __restrict__ l,
                         const float* __restrict__ hemi,
                         const float* __restrict__ V,
                         const int* __restrict__ indices,
                         const int* __restrict__ pointindex,
                         const float* __restrict__ COL,
                         const float* __restrict__ OPA,
                         double* __restrict__ ws,
                         unsigned* __restrict__ emptyMask,
                         float* __restrict__ out) {
    const int b = blockIdx.x, t = threadIdx.x;
    float* __restrict__ f32w = (float*)((char*)ws + F32_BYTE_OFF);
    if (b < 50) {
        int idx = b * 256 + t;                 // < 12800 exactly
        int pi = idx / NS, si = idx % NS;
        double px = p[pi*3+0], py = p[pi*3+1], pz = p[pi*3+2];
        double lx = l[0], ly = l[1], lz = l[2];
        double ux = lx - px, uy = ly - py, uz = lz - pz;
        double nrm = sqrt(ux*ux + uy*uy + uz*uz);
        ux /= nrm; uy /= nrm; uz /= nrm;
        double c = -uy;
        double wx = -uz, wz = ux;              // w = cross((0,-1,0), u_hat), wy=0
        double m01 = -wz, m10 = wz, m12 = -wx, m21 = wx;
        double q00 = m01*m10;
        double q02 = m01*m12;
        double q11 = m10*m01 + m12*m21;
        double q20 = m21*m10;
        double q22 = m21*m12;
        double ic = 1.0 + c;
        double r00 = 1.0 + q00/ic, r01 = m01,            r02 = q02/ic;
        double r10 = m10,          r11 = 1.0 + q11/ic,   r12 = m12;
        double r20 = q20/ic,       r21 = m21,            r22 = 1.0 + q22/ic;
        double hx = hemi[si*3+0], hy = hemi[si*3+1], hz = hemi[si*3+2];
        double dx = r00*hx + r01*hy + r02*hz + lx - px;
        double dy = r10*hx + r11*hy + r12*hz + ly - py;
        double dz = r20*hx + r21*hy + r22*hz + lz - pz;
        double* dsA = ws + DSA_OFF;
        dsA[idx*4+0] = dx;
        dsA[idx*4+1] = dy;
        dsA[idx*4+2] = dz;
        dsA[idx*4+3] = 0.0;
        *(float4*)(f32w + FD_OFF + idx*4) =
            make_float4((float)dx, (float)dy, (float)dz, 0.0f);
    } else if (b < 54) {
        int n = (b - 50) * 256 + t;            // < 1024 exactly
        const float* v = V + n*12;
        double a0=v[0], a1=v[1], a2=v[2];
        double b0=v[3], b1=v[4], b2=v[5];
        double c0=v[6], c1=v[7], c2=v[8];
        double v3x=v[9], v3y=v[10], v3z=v[11];
        double e1x=b0-a0, e1y=b1-a1, e1z=b2-a2;
        double e2x=c0-a0, e2y=c1-a1, e2z=c2-a2;
        double cx = e1y*e2z - e1z*e2y;
        double cy = e1z*e2x - e1x*e2z;
        double cz = e1x*e2y - e1y*e2x;
        double nn = sqrt(cx*cx + cy*cy + cz*cz);
        double nx = cx/nn, ny = cy/nn, nz = cz/nn;
        double kk = -(nx*v3x + ny*v3y + nz*v3z);
        double Bv = a0*b2 - a2*b0;
        double Dv = a0*b1 - a1*b0;
        double Ec = a0*c2 - a2*c0;
        double G2 = a1*c0 - a0*c1;
        double Fc = Bv*G2;
        double gd = Dv*(Ec*Dv + Fc);
        double gq = Dv*gd;
        double dq = Dv*c0;
        double aq = a0*gq;
        double WGr0 = a1*Bv - a2*Dv, WGr1 = -(a0*Bv), WGr2 = a0*Dv;
        double dg = Dv*G2;
        double WBr0 = -(a1*gd) + dg*WGr0;
        double WBr1 =  a0*gd  + dg*WGr1;
        double WBr2 =            dg*WGr2;
        double dd = Dv*dq;
        double WAr0 = gq - b0*WBr0 - dd*WGr0;
        double WAr1 =    - b0*WBr1 - dd*WGr1;
        double WAr2 =    - b0*WBr2 - dd*WGr2;
        double sg = sgn(Dv*gd), sb = sgn(gq), sa = sgn(aq);
        ws[NX_OFF + n] = nx;
        ws[NY_OFF + n] = ny;
        ws[NZ_OFF + n] = nz;
        ws[KK_OFF + n] = kk;
        double g0 = WGr0*sg, g1 = WGr1*sg, g2 = WGr2*sg;
        double bb0 = WBr0*sb, bb1 = WBr1*sb, bb2 = WBr2*sb;
        double aa0 = WAr0*sa, aa1 = WAr1*sa, aa2 = WAr2*sa;
        double* W = ws + W_OFF + n*10;
        W[0]=g0; W[1]=g1; W[2]=g2;
        W[3]=bb0; W[4]=bb1; W[5]=bb2;
        W[6]=aa0; W[7]=aa1; W[8]=aa2;
        W[9]=0.0;
        // f32 shadows
        f32w[FNX_OFF+n]=(float)nx; f32w[FNY_OFF+n]=(float)ny;
        f32w[FNZ_OFF+n]=(float)nz; f32w[FKK_OFF+n]=(float)kk;
        double wsg = fabs(g0)+fabs(g1)+fabs(g2);
        double wsb = fabs(bb0)+fabs(bb1)+fabs(bb2);
        double wsa = fabs(aa0)+fabs(aa1)+fabs(aa2);
        double ig = wsg>0.0 ? 1.0/wsg : 0.0;
        double ib = wsb>0.0 ? 1.0/wsb : 0.0;
        double ia = wsa>0.0 ? 1.0/wsa : 0.0;
        float* fw = f32w + FW_OFF + n*12;
        fw[0]=(float)(g0*ig);  fw[1]=(float)(g1*ig);  fw[2]=(float)(g2*ig);
        fw[3]=(float)(bb0*ib); fw[4]=(float)(bb1*ib); fw[5]=(float)(bb2*ib);
        fw[6]=(float)(aa0*ia); fw[7]=(float)(aa1*ia); fw[8]=(float)(aa2*ia);
        fw[9]=0.0f; fw[10]=0.0f; fw[11]=0.0f;
    } else {
        emptyMask[t] = 0u;
        emptyMask[t + 256] = 0u;
        __syncthreads();
        for (int i = t; i < NP; i += 256) {
            int pidx = pointindex[i];
            int local = pidx & (NP - 1);
            int surf = indices[pidx*2 + 0];
            int mat  = indices[pidx*2 + 1];
            atomicOr(&emptyMask[local], 1u << surf);
            float* colOut = out + MASKN;
            float* opaOut = out + MASKN + 3*NP;
            float* refOut = out + MASKN + 4*NP;
            colOut[i*3+0] = COL[(surf*8+mat)*3+0];
            colOut[i*3+1] = COL[(surf*8+mat)*3+1];
            colOut[i*3+2] = COL[(surf*8+mat)*3+2];
            float o = OPA[surf*8+mat];
            opaOut[i] = fminf(fmaxf(o, 0.0f), 1.0f);
            refOut[i*3+0] = (float)((double)l[0] - (double)p[i*3+0]);
            refOut[i*3+1] = (float)((double)l[1] - (double)p[i*3+1]);
            refOut[i*3+2] = (float)((double)l[2] - (double)p[i*3+2]);
            double* pd = ws + PD_OFF;
            pd[i*4+0] = (double)p[i*3+0];
            pd[i*4+1] = (double)p[i*3+1];
            pd[i*4+2] = (double)p[i*3+2];
            pd[i*4+3] = 0.0;
            *(float4*)(f32w + FPD_OFF + i*4) =
                make_float4(p[i*3+0], p[i*3+1], p[i*3+2], 0.0f);
        }
    }
}

// Exact f64 recheck for flagged (borderline) elements — identical math to the
// validated round-4..6 f64 pipeline.
__device__ __forceinline__ float recheck64(const double* __restrict__ ws,
        unsigned ps, unsigned pp, unsigned i, unsigned nn, unsigned ss,
        unsigned em) {
    const double* s = ws + DSA_OFF + ps*4u;
    const double* o = ws + PD_OFF + pp*4u;
    double nx = ws[NX_OFF+i], ny = ws[NY_OFF+i], nz = ws[NZ_OFF+i];
    double kk = ws[KK_OFF+i];
    double vd = fma(s[2], nz, fma(s[1], ny, s[0]*nx));
    double tt = fma(o[2], nz, fma(o[1], ny, fma(o[0], nx, kk)));
    double e1 = fma(1e-4, vd, -tt);
    double e2 = vd + tt;
    const double* d = ws + DSA_OFF + (pp*25u + ss)*4u;
    double R0 = fma(-tt, d[0], vd*o[0]);
    double R1 = fma(-tt, d[1], vd*o[1]);
    double R2 = fma(-tt, d[2], vd*o[2]);
    const double* w = ws + W_OFF + nn*10u;
    double dG = fma(R2, w[2], fma(R1, w[1], R0*w[0]));
    double dB = fma(R2, w[5], fma(R1, w[4], R0*w[3]));
    double dA = fma(R2, w[8], fma(R1, w[7], R0*w[6]));
    int hv = __double2hiint(vd);
    int m = (__double2hiint(e1)^hv) | (__double2hiint(e2)^hv)
          | (__double2hiint(dG)^hv) | (__double2hiint(dB)^hv)
          | (__double2hiint(dA)^hv);
    bool ok = (m >= 0) && !((nn < 8u) && ((em >> nn) & 1u));
    return ok ? 1.0f : 0.0f;
}

__global__ __launch_bounds__(256, 4) void diffuse_main(
        const double* __restrict__ ws,
        const unsigned* __restrict__ emptyMask,
        float* __restrict__ out) {
    __shared__ float sW[42][12];
    __shared__ float sdx[25], sdy[25], sdz[25], sdm[25];

    const float* __restrict__ f32 = (const float*)((const char*)ws + F32_BYTE_OFF);
    const unsigned ps = blockIdx.x;
    const unsigned pp = ps / 25u;
    const unsigned q  = ps - pp*25u;
    const unsigned nn0 = (q << 10) / 25u;
    const unsigned tid = threadIdx.x;
    const unsigned n0 = tid * 4u;

    // per-thread coalesced table loads (f32)
    const float4 fnx = *(const float4*)(f32 + FNX_OFF + n0);
    const float4 fny = *(const float4*)(f32 + FNY_OFF + n0);
    const float4 fnz = *(const float4*)(f32 + FNZ_OFF + n0);
    const float4 fkk = *(const float4*)(f32 + FKK_OFF + n0);
    // block-uniform scalars
    const float sx = f32[FD_OFF + ps*4u + 0];
    const float sy = f32[FD_OFF + ps*4u + 1];
    const float sz = f32[FD_OFF + ps*4u + 2];
    const float ox = f32[FPD_OFF + pp*4u + 0];
    const float oy = f32[FPD_OFF + pp*4u + 1];
    const float oz = f32[FPD_OFF + pp*4u + 2];
    const unsigned em = (q == 0u) ? emptyMask[pp] : 0u;
    const float S1u = fabsf(sx) + fabsf(sy) + fabsf(sz);
    const float O1u = fabsf(ox) + fabsf(oy) + fabsf(oz);
    const float Evd = CEPS * S1u;
    const float Eb0 = S1u + O1u;          // e1/e2 magnitude base
    const float SOu = S1u * O1u;          // vd*o magnitude base for R

    // stage W window (42 rows x 12 floats) + ray d-vectors
    if (tid < 126u) {
        unsigned row = tid / 3u, quad = tid - row*3u;
        unsigned gn = nn0 + row; if (gn > 1023u) gn = 1023u;
        const float4 v = *(const float4*)(f32 + FW_OFF + gn*12u + quad*4u);
        *(float4*)(&sW[row][quad*4u]) = v;
    }
    if (tid < 25u) {
        const float4 dr = *(const float4*)(f32 + FD_OFF + (pp*25u + tid)*4u);
        sdx[tid] = dr.x; sdy[tid] = dr.y; sdz[tid] = dr.z;
        sdm[tid] = fmaxf(fabsf(dr.x), fmaxf(fabsf(dr.y), fabsf(dr.z)));
    }
    __syncthreads();

    const float nxk[4] = {fnx.x, fnx.y, fnx.z, fnx.w};
    const float nyk[4] = {fny.x, fny.y, fny.z, fny.w};
    const float nzk[4] = {fnz.x, fnz.y, fnz.z, fnz.w};
    const float kkk[4] = {fkk.x, fkk.y, fkk.z, fkk.w};

    unsigned rem = (q << 10) + n0;
    unsigned nn = rem / 25u;
    unsigned ss = rem - nn*25u;

    float res[4];
    #pragma unroll
    for (int k = 0; k < 4; ++k) {
        const float nx = nxk[k], ny = nyk[k], nz = nzk[k], kk = kkk[k];
        const float vd = fmaf(sz, nz, fmaf(sy, ny, sx*nx));
        const float tt = fmaf(oz, nz, fmaf(oy, ny, fmaf(ox, nx, kk)));
        const float e1 = fmaf(1e-4f, vd, -tt);     // t > -1e-4
        const float e2 = vd + tt;                  // t < 1

        const float dxv = sdx[ss], dyv = sdy[ss], dzv = sdz[ss], dmv = sdm[ss];
        const float R0 = fmaf(-tt, dxv, vd*ox);
        const float R1 = fmaf(-tt, dyv, vd*oy);
        const float R2 = fmaf(-tt, dzv, vd*oz);

        const float* w = sW[nn - nn0];
        const float dG = fmaf(R2, w[2], fmaf(R1, w[1], R0*w[0]));
        const float dB = fmaf(R2, w[5], fmaf(R1, w[4], R0*w[3]));
        const float dA = fmaf(R2, w[8], fmaf(R1, w[7], R0*w[6]));

        const int hv = __float_as_int(vd);
        int msk = (__float_as_int(e1)^hv) | (__float_as_int(e2)^hv)
                | (__float_as_int(dG)^hv) | (__float_as_int(dB)^hv)
                | (__float_as_int(dA)^hv);
        bool ok = (msk >= 0) && !((nn < 8u) && ((em >> nn) & 1u));

        // --- rounding-error guards (magnitude-based, cancellation-safe) ---
        const float akk = fabsf(kk);
        const float Ee  = CEPS * (Eb0 + akk);               // e1,e2 bound
        const float Mtt = O1u + akk;                        // >= |tt| and err scale
        const float MR  = fmaf(Mtt, dmv, SOu);              // >= |R_i| and err scale
        const float Edx = CEPS * MR;                        // dG/dB/dA bound (sum|w|=1)
        const float mind = fminf(fabsf(dG), fminf(fabsf(dB), fabsf(dA)));
        const bool flag = (fabsf(vd) < Evd) | (fabsf(e1) < Ee)
                        | (fabsf(e2) < Ee) | (mind < Edx);

        float r = ok ? 1.0f : 0.0f;
        if (__builtin_expect(flag, 0))
            r = recheck64(ws, ps, pp, n0 + (unsigned)k, nn, ss, em);
        res[k] = r;

        ss += 1u;
        const bool wrap = (ss == 25u);
        nn += wrap ? 1u : 0u;
        ss  = wrap ? 0u : ss;
    }
    *(float4*)(out + (ps << 10) + n0) = make_float4(res[0], res[1], res[2], res[3]);
}

extern "C" void kernel_launch(void* const* d_in, const int* in_sizes, int n_in,
                              void* d_out, int out_size, void* d_ws, size_t ws_size,
                              hipStream_t stream) {
    const float* V         = (const float*)d_in[0];
    const int*   indices   = (const int*)  d_in[1];
    const int*   pointindex= (const int*)  d_in[2];
    const float* COL       = (const float*)d_in[3];
    const float* OPA       = (const float*)d_in[4];
    const float* p         = (const float*)d_in[5];
    const float* l         = (const float*)d_in[6];
    // d_in[7] = normals (unused), d_in[8] = it (unused)
    const float* hemi      = (const float*)d_in[9];

    float* out = (float*)d_out;
    double* ws = (double*)d_ws;
    unsigned* emptyMask = (unsigned*)((char*)d_ws + EMPTY_OFF);

    prep_all<<<55, 256, 0, stream>>>(p, l, hemi, V, indices, pointindex,
                                     COL, OPA, ws, emptyMask, out);
    diffuse_main<<<NPS, 256, 0, stream>>>(ws, emptyMask, out);
}